// Round 7
// baseline (358.540 us; speedup 1.0000x reference)
//
#include <hip/hip_runtime.h>
#include <math.h>

#define HW (128*128)

typedef short short8 __attribute__((ext_vector_type(8)));
typedef float floatx4 __attribute__((ext_vector_type(4)));

#define MFMA(a,b,c) __builtin_amdgcn_mfma_f32_16x16x32_bf16((a),(b),(c),0,0,0)

// workspace: [wt2: bf16 main weight 64x864][wmt: fp32 offset weight 594*27]
#define WT2_ELEMS  (64*864)          // [o][kk*96 + c], zero for c>=66
#define WT2_BYTES  (WT2_ELEMS*2)
#define WMT_ELEMS  (594*27)          // [(c*9+j)*27 + oc]
#define WS_NEED    (WT2_BYTES + WMT_ELEMS*4)

static __device__ __forceinline__ unsigned short f2bf(float x) {
    unsigned u = __float_as_uint(x);
    unsigned r = u + 0x7FFFu + ((u >> 16) & 1u);
    return (unsigned short)(r >> 16);
}

__global__ __launch_bounds__(256) void prep_w(
    const float* __restrict__ weight, const float* __restrict__ w_om,
    unsigned short* __restrict__ wt2, float* __restrict__ wmt)
{
    int t = blockIdx.x * 256 + threadIdx.x;
    if (t < WT2_ELEMS) {
        int o = t / 864, k = t % 864;
        int kk = k / 96, c = k % 96;
        float v = (c < 66) ? weight[o * 594 + c * 9 + kk] : 0.0f;
        wt2[t] = f2bf(v);
    } else if (t < WT2_ELEMS + WMT_ELEMS) {
        int t2 = t - WT2_ELEMS;
        int oc = t2 % 27, ck = t2 / 27;
        wmt[t2] = w_om[oc * 594 + ck];
    }
}

// Phase A: fp32 VALU offset conv (verified round 2/5).
// Phase B: fp32 cols in LDS (stride 108), register f2bf, bf16 MFMA.
//   NOTE (r3/r4/r6 post-mortem): storing bf16-packed cols in LDS fails
//   correctness 3/3 times (0.12-0.23 absmax); fp32-LDS + register-convert
//   is bitwise-verified. Do not "optimize" this back to bf16 LDS.
// Wave-owns-px-tile: wave wu holds B-fragments of px tile wu (converted once),
// loops over 4 o-tiles with A from L2-hot wt2 -> 4x less f2bf + LDS traffic.
// XCD swizzle: bid&7 = batch -> each XCD's L2 keeps one batch's row window.
__global__ __launch_bounds__(256, 4) void dcn_hybrid4(
    const float* __restrict__ input,
    const unsigned short* __restrict__ wt2,
    const float* __restrict__ bias,
    const float* __restrict__ wmt,
    const float* __restrict__ b_om,
    float* __restrict__ out)
{
    __shared__ __align__(16) float s_red[4 * 27 * 64];   // 6912 floats; Phase B: cols [64][108]
    __shared__ float s_offh[9 * 64], s_offw[9 * 64], s_maskf[9 * 64];

    const int tid  = threadIdx.x;
    const int lane = tid & 63;
    const int w    = tid >> 6;
    const int wu   = __builtin_amdgcn_readfirstlane(w);
    const int m15  = lane & 15;
    const int quad = lane >> 4;

    // ---- XCD swizzle: batch per XCD, y-sequential within XCD
    const int bid = blockIdx.x;
    const int b   = bid & 7;
    const int jj  = bid >> 3;
    const int wo0 = (jj & 1) * 64;
    const int ho  = jj >> 1;

    const int wo  = wo0 + lane;
    const int p   = ho * 128 + wo;
    const float invH = 1.0f / 128.0f;

    const float* inb = input + (size_t)b * 64 * HW;

    // ---- 9 fixed-tap addresses / validity for pixel (ho, wo)
    int   a9[9];
    float okf[9], vy[9], vx[9];
#pragma unroll
    for (int j = 0; j < 9; ++j) {
        int y = ho - 1 + j / 3;
        int x = wo - 1 + j % 3;
        bool ok = ((unsigned)y < 128u) && ((unsigned)x < 128u);
        int yc = min(max(y, 0), 127), xc = min(max(x, 0), 127);
        a9[j]  = yc * 128 + xc;
        okf[j] = ok ? 1.0f : 0.0f;
        vy[j]  = ok ? y * invH : 0.0f;
        vx[j]  = ok ? (x * invH - 0.5f) : 0.0f;
    }

    const int nc = (wu < 2) ? 17 : 16;     // channels per wave: c = wu + 4*i

    // ---------------- Phase A: fp32 partial offset conv ----------------
    float om_part[27];
#pragma unroll
    for (int oc = 0; oc < 27; ++oc) om_part[oc] = 0.0f;

    for (int i = 0; i < nc; ++i) {
        int c = wu + 4 * i;
        float v[9];
        if (c < 64) {
            const float* pc = inb + c * HW;
#pragma unroll
            for (int j = 0; j < 9; ++j) v[j] = pc[a9[j]] * okf[j];
        } else if (c == 64) {
#pragma unroll
            for (int j = 0; j < 9; ++j) v[j] = vy[j];
        } else {
#pragma unroll
            for (int j = 0; j < 9; ++j) v[j] = vx[j];
        }
#pragma unroll
        for (int j = 0; j < 9; ++j) {
            const float* wp = wmt + (c * 9 + j) * 27;
#pragma unroll
            for (int oc = 0; oc < 27; ++oc)
                om_part[oc] = fmaf(v[j], wp[oc], om_part[oc]);
        }
    }
#pragma unroll
    for (int oc = 0; oc < 27; ++oc)
        s_red[(w * 27 + oc) * 64 + lane] = om_part[oc];
    __syncthreads();

    // ---- 4-way reduce + idx/mask epilogue + fp32 offsets/mask into LDS
    {
        float* out_idx = out + (size_t)8 * 64 * HW;
        float* out_msk = out_idx + (size_t)8 * 18 * HW;
        const float hg = ho * invH;
        const float wg = wo * invH - 0.5f;
        int oc0 = wu * 7;
        int noc = (wu == 3) ? 6 : 7;
        for (int t = 0; t < noc; ++t) {
            int oc = oc0 + t;
            float s = b_om[oc]
                    + s_red[(0 * 27 + oc) * 64 + lane]
                    + s_red[(1 * 27 + oc) * 64 + lane]
                    + s_red[(2 * 27 + oc) * 64 + lane]
                    + s_red[(3 * 27 + oc) * 64 + lane];
            if (oc < 9) {
                out_idx[((size_t)b * 18 + oc) * HW + p] = hg + (float)(oc / 3 - 1) + s;
                if (oc & 1) s_offw[(oc >> 1) * 64 + lane] = s;
                else        s_offh[(oc >> 1) * 64 + lane] = s;
            } else if (oc < 18) {
                out_idx[((size_t)b * 18 + oc) * HW + p] = wg + (float)((oc - 9) % 3 - 1) + s;
                if (oc & 1) s_offw[(oc >> 1) * 64 + lane] = s;
                else        s_offh[(oc >> 1) * 64 + lane] = s;
            } else {
                float mkv = 1.0f / (1.0f + __expf(-s));
                out_msk[((size_t)b * 9 + (oc - 18)) * HW + p] = mkv;
                s_maskf[(oc - 18) * 64 + lane] = mkv;
            }
        }
    }
    __syncthreads();   // s_red reads done; offsets/mask ready; s_red reusable

    // ---------------- Phase B: fp32 cols in LDS + bf16 MFMA ----------------
    float* s_colf = s_red;   // [64 px][108 floats]

    // zero the K-pad region c in [66,96)
    for (int z = 0; z < 8; ++z) {
        int cz = 66 + 8 * wu + z;
        if (cz < 96) s_colf[lane * 108 + cz] = 0.0f;
    }

    floatx4 acc[4];
#pragma unroll
    for (int t = 0; t < 4; ++t) acc[t] = (floatx4){0.f, 0.f, 0.f, 0.f};

    for (int kk = 0; kk < 9; ++kk) {
        if (kk) __syncthreads();   // previous MFMA reads done before overwrite

        {   // ---- build fp32 cols for tap kk (pixel = lane, channels of wave wu)
            float offh = s_offh[kk * 64 + lane];
            float offw = s_offw[kk * 64 + lane];
            float mval = s_maskf[kk * 64 + lane];

            float ph = offh + (float)(kk / 3) + (float)(ho - 1);
            float pw = offw + (float)(kk % 3) + (float)(wo - 1);
            float h0f = floorf(ph), w0f = floorf(pw);
            int h0 = (int)h0f, w0 = (int)w0f;
            int h1 = h0 + 1, w1 = w0 + 1;
            float lh = ph - h0f, lw = pw - w0f;
            float hh = 1.0f - lh, hwp = 1.0f - lw;
            bool okh0 = (unsigned)h0 < 128u, okh1 = (unsigned)h1 < 128u;
            bool okw0 = (unsigned)w0 < 128u, okw1 = (unsigned)w1 < 128u;
            float w00 = (okh0 && okw0) ? hh * hwp * mval : 0.0f;
            float w01 = (okh0 && okw1) ? hh * lw  * mval : 0.0f;
            float w10 = (okh1 && okw0) ? lh * hwp * mval : 0.0f;
            float w11 = (okh1 && okw1) ? lh * lw  * mval : 0.0f;
            int h0c = min(max(h0, 0), 127), h1c = min(max(h1, 0), 127);
            int w0c = min(max(w0, 0), 127), w1c = min(max(w1, 0), 127);
            int o00 = h0c * 128 + w0c, o01 = h0c * 128 + w1c;
            int o10 = h1c * 128 + w0c, o11 = h1c * 128 + w1c;

            float* row = s_colf + lane * 108;
#pragma unroll
            for (int i = 0; i < 8; ++i) {
                int c = wu * 16 + 2 * i;
                const float* p0 = inb + (size_t)c * HW;
                float ca = w00 * p0[o00] + w01 * p0[o01] + w10 * p0[o10] + w11 * p0[o11];
                float cb = w00 * p0[HW + o00] + w01 * p0[HW + o01] + w10 * p0[HW + o10] + w11 * p0[HW + o11];
                row[c]     = ca;
                row[c + 1] = cb;
            }
            if (wu == 3) {
                float y0 = h0c * invH, y1 = h1c * invH;
                float x0 = w0c * invH - 0.5f, x1 = w1c * invH - 0.5f;
                row[64] = (w00 + w01) * y0 + (w10 + w11) * y1;
                row[65] = (w00 + w10) * x0 + (w01 + w11) * x1;
            }
        }
        __syncthreads();   // cols visible to all waves

        // ---- B-fragments for THIS wave's px tile (px = 16*wu + m15), converted once
        short8 B[3];
        {
            const float* rowp = s_colf + (16 * wu + m15) * 108;
#pragma unroll
            for (int ks = 0; ks < 3; ++ks) {
                const float* fp = rowp + ks * 32 + quad * 8;
                floatx4 f0 = *(const floatx4*)&fp[0];
                floatx4 f1 = *(const floatx4*)&fp[4];
                short8 bf;
                bf[0] = (short)f2bf(f0[0]); bf[1] = (short)f2bf(f0[1]);
                bf[2] = (short)f2bf(f0[2]); bf[3] = (short)f2bf(f0[3]);
                bf[4] = (short)f2bf(f1[0]); bf[5] = (short)f2bf(f1[1]);
                bf[6] = (short)f2bf(f1[2]); bf[7] = (short)f2bf(f1[3]);
                B[ks] = bf;
            }
        }

        // ---- loop over o-tiles; A from L2-hot wt2
#pragma unroll
        for (int ot = 0; ot < 4; ++ot) {
#pragma unroll
            for (int ks = 0; ks < 3; ++ks) {
                short8 A = *(const short8*)&wt2[(16 * ot + m15) * 864 + kk * 96 + ks * 32 + quad * 8];
                acc[ot] = MFMA(A, B[ks], acc[ot]);
            }
        }
    }

    // ---------- Phase B epilogue: o = 16*ot + quad*4 + r, px = 16*wu + m15 ----------
    {
        int px = 16 * wu + m15;
        size_t pbase = (size_t)ho * 128 + wo0 + px;
#pragma unroll
        for (int ot = 0; ot < 4; ++ot) {
#pragma unroll
            for (int r = 0; r < 4; ++r) {
                int o = 16 * ot + quad * 4 + r;
                out[((size_t)b * 64 + o) * HW + pbase] = acc[ot][r] + bias[o];
            }
        }
    }
}

// ------------------- fallback (no workspace): fp32 baseline -------------------
__global__ __launch_bounds__(256) void dcn_fb(
    const float* __restrict__ input,
    const float* __restrict__ wmain,
    const float* __restrict__ bias,
    const float* __restrict__ wom,
    const float* __restrict__ b_om,
    float* __restrict__ out)
{
    const int wo = blockIdx.x * 64 + threadIdx.x;
    const int ho = blockIdx.y * 4 + threadIdx.y;
    const int b  = blockIdx.z;
    const int p  = ho * 128 + wo;
    const float invH = 1.0f / 128.0f;
    const float* inb = input + (size_t)b * 64 * HW;

    float om[27];
#pragma unroll
    for (int oc = 0; oc < 27; ++oc) om[oc] = b_om[oc];

    for (int c = 0; c < 64; ++c) {
        const float* pc = inb + c * HW;
        float v[9];
#pragma unroll
        for (int kh = 0; kh < 3; ++kh) {
            int y = ho - 1 + kh;
            bool oky = (unsigned)y < 128u;
#pragma unroll
            for (int kw = 0; kw < 3; ++kw) {
                int x = wo - 1 + kw;
                bool ok = oky && ((unsigned)x < 128u);
                v[kh*3+kw] = ok ? pc[y * 128 + x] : 0.0f;
            }
        }
#pragma unroll
        for (int oc = 0; oc < 27; ++oc)
#pragma unroll
            for (int i = 0; i < 9; ++i)
                om[oc] = fmaf(v[i], wom[oc*594 + c*9 + i], om[oc]);
    }
    {
        float v64[9], v65[9];
#pragma unroll
        for (int kh = 0; kh < 3; ++kh) {
            int y = ho - 1 + kh;
            bool oky = (unsigned)y < 128u;
#pragma unroll
            for (int kw = 0; kw < 3; ++kw) {
                int x = wo - 1 + kw;
                bool ok = oky && ((unsigned)x < 128u);
                v64[kh*3+kw] = ok ? y * invH : 0.0f;
                v65[kh*3+kw] = ok ? (x * invH - 0.5f) : 0.0f;
            }
        }
#pragma unroll
        for (int oc = 0; oc < 27; ++oc)
#pragma unroll
            for (int i = 0; i < 9; ++i) {
                om[oc] = fmaf(v64[i], wom[oc*594 + 64*9 + i], om[oc]);
                om[oc] = fmaf(v65[i], wom[oc*594 + 65*9 + i], om[oc]);
            }
    }

    const float hg = ho * invH;
    const float wg = wo * invH - 0.5f;
    float* out_idx = out + (size_t)8 * 64 * HW;
    float* out_msk = out_idx + (size_t)8 * 18 * HW;
#pragma unroll
    for (int cc = 0; cc < 9; ++cc)
        out_idx[((size_t)b*18 + cc)*HW + p] = hg + (float)(cc/3 - 1) + om[cc];
#pragma unroll
    for (int cc = 9; cc < 18; ++cc)
        out_idx[((size_t)b*18 + cc)*HW + p] = wg + (float)((cc-9)%3 - 1) + om[cc];

    float mk[9];
#pragma unroll
    for (int kk = 0; kk < 9; ++kk) {
        mk[kk] = 1.0f / (1.0f + __expf(-om[18+kk]));
        out_msk[((size_t)b*9 + kk)*HW + p] = mk[kk];
    }

    float acc[64];
#pragma unroll
    for (int o = 0; o < 64; ++o) acc[o] = bias[o];

#pragma unroll
    for (int kk = 0; kk < 9; ++kk) {
        float ph = om[2*kk]   + (float)(kk/3) + (float)(ho - 1);
        float pw = om[2*kk+1] + (float)(kk%3) + (float)(wo - 1);
        float h0f = floorf(ph), w0f = floorf(pw);
        int h0 = (int)h0f, w0 = (int)w0f;
        int h1 = h0 + 1, w1 = w0 + 1;
        float lh = ph - h0f, lw = pw - w0f;
        float hh = 1.0f - lh, hwp = 1.0f - lw;
        float m = mk[kk];
        bool okh0 = (unsigned)h0 < 128u, okh1 = (unsigned)h1 < 128u;
        bool okw0 = (unsigned)w0 < 128u, okw1 = (unsigned)w1 < 128u;
        float w00 = (okh0 && okw0) ? hh*hwp*m : 0.0f;
        float w01 = (okh0 && okw1) ? hh*lw*m  : 0.0f;
        float w10 = (okh1 && okw0) ? lh*hwp*m : 0.0f;
        float w11 = (okh1 && okw1) ? lh*lw*m  : 0.0f;
        int h0c = min(max(h0, 0), 127), h1c = min(max(h1, 0), 127);
        int w0c = min(max(w0, 0), 127), w1c = min(max(w1, 0), 127);
        int o00 = h0c*128 + w0c, o01 = h0c*128 + w1c;
        int o10 = h1c*128 + w0c, o11 = h1c*128 + w1c;

        for (int c = 0; c < 64; ++c) {
            const float* pc = inb + c * HW;
            float col = w00*pc[o00] + w01*pc[o01] + w10*pc[o10] + w11*pc[o11];
#pragma unroll
            for (int o = 0; o < 64; ++o)
                acc[o] = fmaf(col, wmain[o*594 + c*9 + kk], acc[o]);
        }
        {
            float y0 = h0c * invH, y1 = h1c * invH;
            float x0 = w0c * invH - 0.5f, x1 = w1c * invH - 0.5f;
            float col64 = (w00 + w01)*y0 + (w10 + w11)*y1;
            float col65 = (w00 + w10)*x0 + (w01 + w11)*x1;
#pragma unroll
            for (int o = 0; o < 64; ++o) {
                acc[o] = fmaf(col64, wmain[o*594 + 64*9 + kk], acc[o]);
                acc[o] = fmaf(col65, wmain[o*594 + 65*9 + kk], acc[o]);
            }
        }
    }

#pragma unroll
    for (int o = 0; o < 64; ++o)
        out[((size_t)b*64 + o)*HW + p] = acc[o];
}

extern "C" void kernel_launch(void* const* d_in, const int* in_sizes, int n_in,
                              void* d_out, int out_size, void* d_ws, size_t ws_size,
                              hipStream_t stream)
{
    const float* input  = (const float*)d_in[0];
    const float* weight = (const float*)d_in[1];
    const float* bias   = (const float*)d_in[2];
    const float* w_om   = (const float*)d_in[3];
    const float* b_om   = (const float*)d_in[4];
    float* out = (float*)d_out;

    if (ws_size >= (size_t)WS_NEED) {
        unsigned short* wt2 = (unsigned short*)d_ws;
        float* wmt = (float*)((char*)d_ws + WT2_BYTES);
        int total = WT2_ELEMS + WMT_ELEMS;
        prep_w<<<(total + 255) / 256, 256, 0, stream>>>(weight, w_om, wt2, wmt);
        dcn_hybrid4<<<dim3(2048, 1, 1), dim3(256, 1, 1), 0, stream>>>(input, wt2, bias, wmt, b_om, out);
    } else {
        dim3 grid(2, 32, 8);
        dcn_fb<<<grid, dim3(64, 4, 1), 0, stream>>>(input, weight, bias, w_om, b_om, out);
    }
}